// Round 15
// baseline (141.214 us; speedup 1.0000x reference)
//
#include <hip/hip_runtime.h>
#include <utility>

#define D_DIM 256
#define WID   33
#define CEN   16
#define RSTR  32                   // rows per block (512*32 = N exactly)
#define WINW  (RSTR + WID - 1)     // 64-row x window
#define PRE   41                   // upfront prefetch; row k issues W[41+k]

// R14 post-mortem: OccupancyPercent 51% == the __launch_bounds__(256,4) cap
// (16/32 waves per CU) while VGPR=48 fits 8 waves/EU. Seven rounds ran at
// half occupancy. Single change vs R14: min-waves 4 -> 8 (VGPR budget 64,
// current usage 48 fits). 2x resident waves = 2x outstanding bytes + 2x
// issue overlap; memory floor ~39us, VALU ~30us.

__device__ __forceinline__ float rdlane(float v, int l) {
    return __uint_as_float(__builtin_amdgcn_readlane(__float_as_uint(v), l));
}

__device__ __forceinline__ int clampN(int p, int N) {
    return p < 0 ? 0 : (p >= N ? N - 1 : p);
}

template <size_t... Is>
__device__ __forceinline__ void load_head(float (&W)[WINW],
                                          const float* __restrict__ xb,
                                          int base, int N,
                                          std::index_sequence<Is...>) {
    ((W[Is] = xb[(size_t)clampN(base + (int)Is, N) * D_DIM]), ...);
}

template <size_t... Rs>
__device__ __forceinline__ void load_w(float (&wv)[RSTR],
                                       const float* __restrict__ smb,
                                       int n0, int minl,
                                       std::index_sequence<Rs...>) {
    ((wv[Rs] = smb[(size_t)(n0 + (int)Rs) * WID + minl]), ...);
}

template <size_t... Rs>
__device__ __forceinline__ void zero_bad_w(float (&wv)[RSTR], int n0, int lane,
                                           int N, std::index_sequence<Rs...>) {
    ((wv[Rs] = ((unsigned)(n0 + (int)Rs - CEN + lane) < (unsigned)N)
                   ? wv[Rs] : 0.0f),
     ...);
}

template <int K, size_t... Is>
__device__ __forceinline__ float dot_row(const float (&W)[WINW], float wrow,
                                         std::index_sequence<Is...>) {
    float acc[4] = {0.f, 0.f, 0.f, 0.f};
    ((acc[Is & 3] = fmaf(W[K + (int)Is], rdlane(wrow, (int)Is), acc[Is & 3])),
     ...);
    return (acc[0] + acc[1]) + (acc[2] + acc[3]);
}

template <int K>
__device__ __forceinline__ void row_step(float (&W)[WINW], const float (&wv)[RSTR],
                                         float szv, float* __restrict__ ob,
                                         const float* __restrict__ xb,
                                         int base, int N) {
    if constexpr (PRE + K < WINW) {        // pipelined load, 9-row lookahead
        const int p = base + PRE + K;      // >= 25, only upper clamp needed
        W[PRE + K] = xb[(size_t)(p >= N ? N - 1 : p) * D_DIM];
    }
    __builtin_amdgcn_sched_barrier(0);     // pin: no sinking across rows
    const float s   = dot_row<K>(W, wv[K], std::make_index_sequence<WID>{});
    const float inv = __builtin_amdgcn_rcpf(fmaxf(rdlane(szv, K), 1e-6f));
    ob[(size_t)K * D_DIM] = s * inv;
}

template <size_t... Ks>
__device__ __forceinline__ void all_rows(float (&W)[WINW], const float (&wv)[RSTR],
                                         float szv, float* __restrict__ ob,
                                         const float* __restrict__ xb,
                                         int base, int N,
                                         std::index_sequence<Ks...>) {
    (row_step<(int)Ks>(W, wv, szv, ob, xb, base, N), ...);
}

__global__ __launch_bounds__(256, 8) void local_enc_kernel(
    const float* __restrict__ x, const float* __restrict__ sizev,
    const float* __restrict__ sm, float* __restrict__ out, int N) {
    // XCD swizzle: XCD k owns batch k, strips consecutive -> halo L2-local
    const int bid   = blockIdx.x;
    const int swz   = (bid & 7) * 512 + (bid >> 3);
    const int strip = swz & 511;
    const int b     = swz >> 9;
    const int n0    = strip * RSTR;
    const int tid   = threadIdx.x;
    const int lane  = tid & 63;

    const size_t bN = (size_t)b * (size_t)N;
    const float* __restrict__ xb  = x   + bN * D_DIM + tid;
    float*       __restrict__ ob  = out + (bN + (size_t)n0) * D_DIM + tid;
    const float* __restrict__ smb = sm    + bN * WID;
    const float* __restrict__ szb = sizev + bN;

    // issue order: sizes, weights, window head — dot 0 never drains the tail
    const int minl = (lane < WID) ? lane : (WID - 1);
    const float szv = szb[(n0 + minl < N) ? (n0 + minl) : (N - 1)];

    float wv[RSTR];
    load_w(wv, smb, n0, minl, std::make_index_sequence<RSTR>{});
    if (n0 < CEN || n0 + RSTR - 1 + CEN >= N)            // 16 of 4096 blocks
        zero_bad_w(wv, n0, lane, N, std::make_index_sequence<RSTR>{});

    const int base = n0 - CEN;
    float W[WINW];
    load_head(W, xb, base, N, std::make_index_sequence<PRE>{});

    __builtin_amdgcn_sched_barrier(0);
    all_rows(W, wv, szv, ob, xb, base, N, std::make_index_sequence<RSTR>{});
}

extern "C" void kernel_launch(void* const* d_in, const int* in_sizes, int n_in,
                              void* d_out, int out_size, void* d_ws, size_t ws_size,
                              hipStream_t stream) {
    const float* x  = (const float*)d_in[0];
    const float* sz = (const float*)d_in[1];
    const float* sm = (const float*)d_in[2];
    float* out = (float*)d_out;

    const int B = 8;
    const int N = 16384;

    dim3 grid((N / RSTR) * B, 1, 1);   // 4096 blocks, XCD-swizzled
    dim3 block(D_DIM, 1, 1);
    local_enc_kernel<<<grid, block, 0, stream>>>(x, sz, sm, out, N);
}

// Round 16
// 99.723 us; speedup vs baseline: 1.4161x; 1.4161x over previous
//
#include <hip/hip_runtime.h>
#include <utility>

#define D_DIM 256
#define WID   33
#define CEN   16
#define RSTR  32                   // rows per block (512*32 = N exactly)
#define WINW  (RSTR + WID - 1)     // 64-row x window
#define PRE   41                   // upfront prefetch; row k issues W[41+k]

// R15 post-mortem: min-waves=8 -> allocator forced VGPR=32 < the 33-live
// window -> spill (WRITE +147MB), dur 141us. But R13/14/15 A/B shows the
// waves-per-eu knob moves measured occupancy (4 -> ~50%, 8 -> ~82%).
// Window needs ~45 live VGPRs; min-waves=6 gives the allocator an ~85-VGPR
// pressure target: the proven 48-VGPR schedule fits WITHOUT spill while
// raising the occupancy target to 75%. Single-variable change vs R14.

__device__ __forceinline__ float rdlane(float v, int l) {
    return __uint_as_float(__builtin_amdgcn_readlane(__float_as_uint(v), l));
}

__device__ __forceinline__ int clampN(int p, int N) {
    return p < 0 ? 0 : (p >= N ? N - 1 : p);
}

template <size_t... Is>
__device__ __forceinline__ void load_head(float (&W)[WINW],
                                          const float* __restrict__ xb,
                                          int base, int N,
                                          std::index_sequence<Is...>) {
    ((W[Is] = xb[(size_t)clampN(base + (int)Is, N) * D_DIM]), ...);
}

template <size_t... Rs>
__device__ __forceinline__ void load_w(float (&wv)[RSTR],
                                       const float* __restrict__ smb,
                                       int n0, int minl,
                                       std::index_sequence<Rs...>) {
    ((wv[Rs] = smb[(size_t)(n0 + (int)Rs) * WID + minl]), ...);
}

template <size_t... Rs>
__device__ __forceinline__ void zero_bad_w(float (&wv)[RSTR], int n0, int lane,
                                           int N, std::index_sequence<Rs...>) {
    ((wv[Rs] = ((unsigned)(n0 + (int)Rs - CEN + lane) < (unsigned)N)
                   ? wv[Rs] : 0.0f),
     ...);
}

template <int K, size_t... Is>
__device__ __forceinline__ float dot_row(const float (&W)[WINW], float wrow,
                                         std::index_sequence<Is...>) {
    float acc[4] = {0.f, 0.f, 0.f, 0.f};
    ((acc[Is & 3] = fmaf(W[K + (int)Is], rdlane(wrow, (int)Is), acc[Is & 3])),
     ...);
    return (acc[0] + acc[1]) + (acc[2] + acc[3]);
}

template <int K>
__device__ __forceinline__ void row_step(float (&W)[WINW], const float (&wv)[RSTR],
                                         float szv, float* __restrict__ ob,
                                         const float* __restrict__ xb,
                                         int base, int N) {
    if constexpr (PRE + K < WINW) {        // pipelined load, 9-row lookahead
        const int p = base + PRE + K;      // >= 25, only upper clamp needed
        W[PRE + K] = xb[(size_t)(p >= N ? N - 1 : p) * D_DIM];
    }
    __builtin_amdgcn_sched_barrier(0);     // pin: no sinking across rows
    const float s   = dot_row<K>(W, wv[K], std::make_index_sequence<WID>{});
    const float inv = __builtin_amdgcn_rcpf(fmaxf(rdlane(szv, K), 1e-6f));
    ob[(size_t)K * D_DIM] = s * inv;
}

template <size_t... Ks>
__device__ __forceinline__ void all_rows(float (&W)[WINW], const float (&wv)[RSTR],
                                         float szv, float* __restrict__ ob,
                                         const float* __restrict__ xb,
                                         int base, int N,
                                         std::index_sequence<Ks...>) {
    (row_step<(int)Ks>(W, wv, szv, ob, xb, base, N), ...);
}

__global__ __launch_bounds__(256, 6) void local_enc_kernel(
    const float* __restrict__ x, const float* __restrict__ sizev,
    const float* __restrict__ sm, float* __restrict__ out, int N) {
    // XCD swizzle: XCD k owns batch k, strips consecutive -> halo L2-local
    const int bid   = blockIdx.x;
    const int swz   = (bid & 7) * 512 + (bid >> 3);
    const int strip = swz & 511;
    const int b     = swz >> 9;
    const int n0    = strip * RSTR;
    const int tid   = threadIdx.x;
    const int lane  = tid & 63;

    const size_t bN = (size_t)b * (size_t)N;
    const float* __restrict__ xb  = x   + bN * D_DIM + tid;
    float*       __restrict__ ob  = out + (bN + (size_t)n0) * D_DIM + tid;
    const float* __restrict__ smb = sm    + bN * WID;
    const float* __restrict__ szb = sizev + bN;

    // issue order: sizes, weights, window head — dot 0 never drains the tail
    const int minl = (lane < WID) ? lane : (WID - 1);
    const float szv = szb[(n0 + minl < N) ? (n0 + minl) : (N - 1)];

    float wv[RSTR];
    load_w(wv, smb, n0, minl, std::make_index_sequence<RSTR>{});
    if (n0 < CEN || n0 + RSTR - 1 + CEN >= N)            // 16 of 4096 blocks
        zero_bad_w(wv, n0, lane, N, std::make_index_sequence<RSTR>{});

    const int base = n0 - CEN;
    float W[WINW];
    load_head(W, xb, base, N, std::make_index_sequence<PRE>{});

    __builtin_amdgcn_sched_barrier(0);
    all_rows(W, wv, szv, ob, xb, base, N, std::make_index_sequence<RSTR>{});
}

extern "C" void kernel_launch(void* const* d_in, const int* in_sizes, int n_in,
                              void* d_out, int out_size, void* d_ws, size_t ws_size,
                              hipStream_t stream) {
    const float* x  = (const float*)d_in[0];
    const float* sz = (const float*)d_in[1];
    const float* sm = (const float*)d_in[2];
    float* out = (float*)d_out;

    const int B = 8;
    const int N = 16384;

    dim3 grid((N / RSTR) * B, 1, 1);   // 4096 blocks, XCD-swizzled
    dim3 block(D_DIM, 1, 1);
    local_enc_kernel<<<grid, block, 0, stream>>>(x, sz, sm, out, N);
}

// Round 17
// 75.388 us; speedup vs baseline: 1.8732x; 1.3228x over previous
//
#include <hip/hip_runtime.h>
#include <utility>

#define D_DIM 256
#define WID   33
#define CEN   16
#define RWAVE 32                   // rows per wave
#define RBLK  64                   // rows per block (2 row-groups x 2 col-halves)
#define WINW  65                   // window positions 0..64 (rel. to base)
#define PRE   41                   // head loads 0..40; row k issues 41+k

// R16 concluded: occupancy knob always trades the window into spill; best is
// (256,4)@VGPR48, 85us, VALUBusy 46%. Half the VALU instrs are v_readlane.
// This round: each thread owns TWO adjacent columns (float2, dwordx2 loads)
// -> one readlane feeds both columns (VALU/output halved, pk_fma packable),
// memory instr count halved. Same R14 skeleton otherwise.

typedef float f32x2 __attribute__((ext_vector_type(2)));

__device__ __forceinline__ float rdlane(float v, int l) {
    return __uint_as_float(__builtin_amdgcn_readlane(__float_as_uint(v), l));
}

__device__ __forceinline__ int clampN(int p, int N) {
    return p < 0 ? 0 : (p >= N ? N - 1 : p);
}

__device__ __forceinline__ f32x2 ld2(const float* __restrict__ p) {
    return *(const f32x2*)p;
}

template <size_t... Is>
__device__ __forceinline__ void load_head(f32x2 (&W)[WINW],
                                          const float* __restrict__ xw,
                                          int base, int N,
                                          std::index_sequence<Is...>) {
    ((W[Is] = ld2(xw + (size_t)clampN(base + (int)Is, N) * D_DIM)), ...);
}

template <size_t... Rs>
__device__ __forceinline__ void load_w(float (&wvv)[RWAVE],
                                       const float* __restrict__ smb,
                                       int n0w, int minl,
                                       std::index_sequence<Rs...>) {
    ((wvv[Rs] = smb[(size_t)(n0w + (int)Rs) * WID + minl]), ...);
}

template <size_t... Rs>
__device__ __forceinline__ void zero_bad_w(float (&wvv)[RWAVE], int n0w, int lane,
                                           int N, std::index_sequence<Rs...>) {
    ((wvv[Rs] = ((unsigned)(n0w + (int)Rs - CEN + lane) < (unsigned)N)
                    ? wvv[Rs] : 0.0f),
     ...);
}

template <int K, size_t... Is>
__device__ __forceinline__ f32x2 dot_row(const f32x2 (&W)[WINW], float wrow,
                                         std::index_sequence<Is...>) {
    f32x2 a0 = {0.f, 0.f}, a1 = {0.f, 0.f}, a2 = {0.f, 0.f}, a3 = {0.f, 0.f};
    (([&] {
         const float ws = rdlane(wrow, (int)Is);
         const f32x2 xv = W[K + (int)Is];
         f32x2& ac = ((int)Is & 3) == 0 ? a0
                   : ((int)Is & 3) == 1 ? a1
                   : ((int)Is & 3) == 2 ? a2 : a3;
         ac.x = fmaf(xv.x, ws, ac.x);
         ac.y = fmaf(xv.y, ws, ac.y);
     }()),
     ...);
    return (a0 + a1) + (a2 + a3);
}

template <int K>
__device__ __forceinline__ void row_step(f32x2 (&W)[WINW], const float (&wvv)[RWAVE],
                                         float szv, float* __restrict__ ob,
                                         const float* __restrict__ xw,
                                         int base, int N) {
    if constexpr (PRE + K < WINW) {        // pipelined load, 9-row lookahead
        const int p = base + PRE + K;      // >= 25, only upper clamp needed
        W[PRE + K] = ld2(xw + (size_t)(p >= N ? N - 1 : p) * D_DIM);
    }
    __builtin_amdgcn_sched_barrier(0);     // pin: no sinking across rows
    const f32x2 s   = dot_row<K>(W, wvv[K], std::make_index_sequence<WID>{});
    const float inv = __builtin_amdgcn_rcpf(fmaxf(rdlane(szv, K), 1e-6f));
    f32x2 o;
    o.x = s.x * inv;
    o.y = s.y * inv;
    *(f32x2*)(ob + (size_t)K * D_DIM) = o;
}

template <size_t... Ks>
__device__ __forceinline__ void all_rows(f32x2 (&W)[WINW], const float (&wvv)[RWAVE],
                                         float szv, float* __restrict__ ob,
                                         const float* __restrict__ xw,
                                         int base, int N,
                                         std::index_sequence<Ks...>) {
    (row_step<(int)Ks>(W, wvv, szv, ob, xw, base, N), ...);
}

__global__ __launch_bounds__(256, 4) void local_enc_kernel(
    const float* __restrict__ x, const float* __restrict__ sizev,
    const float* __restrict__ sm, float* __restrict__ out, int N) {
    // XCD swizzle: XCD k owns batch k, strips consecutive -> halo L2-local
    const int bid   = blockIdx.x;
    const int swz   = (bid & 7) * 256 + (bid >> 3);
    const int strip = swz & 255;
    const int b     = swz >> 8;
    const int n0    = strip * RBLK;
    const int tid   = threadIdx.x;
    const int wv    = tid >> 6;
    const int lane  = tid & 63;

    const int n0w = n0 + RWAVE * (wv >> 1);        // this wave's 32 rows
    const int cp  = ((wv & 1) * 64 + lane) * 2;    // this thread's column pair

    const size_t bN = (size_t)b * (size_t)N;
    const float* __restrict__ xw  = x   + bN * D_DIM + cp;
    float*       __restrict__ ob  = out + (bN + (size_t)n0w) * D_DIM + cp;
    const float* __restrict__ smb = sm    + bN * WID;
    const float* __restrict__ szb = sizev + bN;

    const int minl = (lane < WID) ? lane : (WID - 1);
    const float szv = szb[(n0w + minl < N) ? (n0w + minl) : (N - 1)];

    float wvv[RWAVE];
    load_w(wvv, smb, n0w, minl, std::make_index_sequence<RWAVE>{});
    if (n0w < CEN || n0w + RWAVE - 1 + CEN >= N)   // boundary waves only
        zero_bad_w(wvv, n0w, lane, N, std::make_index_sequence<RWAVE>{});

    const int base = n0w - CEN;
    f32x2 W[WINW];
    load_head(W, xw, base, N, std::make_index_sequence<PRE>{});

    __builtin_amdgcn_sched_barrier(0);
    all_rows(W, wvv, szv, ob, xw, base, N, std::make_index_sequence<RWAVE>{});
}

extern "C" void kernel_launch(void* const* d_in, const int* in_sizes, int n_in,
                              void* d_out, int out_size, void* d_ws, size_t ws_size,
                              hipStream_t stream) {
    const float* x  = (const float*)d_in[0];
    const float* sz = (const float*)d_in[1];
    const float* sm = (const float*)d_in[2];
    float* out = (float*)d_out;

    const int B = 8;
    const int N = 16384;

    dim3 grid((N / RBLK) * B, 1, 1);   // 2048 blocks, XCD-swizzled
    dim3 block(D_DIM, 1, 1);
    local_enc_kernel<<<grid, block, 0, stream>>>(x, sz, sm, out, N);
}